// Round 4
// baseline (169.514 us; speedup 1.0000x reference)
//
#include <hip/hip_runtime.h>
#include <hip/hip_bf16.h>
#include <math.h>

#define B_ROWS 4096
#define D_DIM  256
#define N_TOT  8192            // 2B
#define E2     7.38905609893065f   // exp(2) = diagonal term of the row sum
#define NT64   128             // 8192 / 64
#define NPAIR  (NT64 * (NT64 + 1) / 2)   // 8256 upper-triangle 64x64 tile pairs
#define WPB    4               // waves per block
#define NBLK2  (NPAIR / WPB)   // 2064 blocks (exact: 8256 = 4*2064)

typedef __attribute__((ext_vector_type(4))) float f32x4;
typedef __attribute__((ext_vector_type(8))) short bf16x8;   // 8 bf16 in 4 VGPRs

// ---------------------------------------------------------------------------
// Kernel 1: per-row L2-normalize query & pos -> bf16 Z[8192][256]; per-row
// positive dot to pospart[row]. Blocks 0..31 also zero denom[8192].
// ---------------------------------------------------------------------------
__global__ __launch_bounds__(256) void norm_kernel(
        const float* __restrict__ q, const float* __restrict__ p,
        __hip_bfloat16* __restrict__ Z, float* __restrict__ pospart,
        float* __restrict__ denom) {
    const int row = blockIdx.x;          // 0..4095
    const int t   = threadIdx.x;         // 0..255
    if (row < 32) denom[row * 256 + t] = 0.0f;
    const float qv = q[row * D_DIM + t];
    const float pv = p[row * D_DIM + t];
    float a = qv * qv, b = pv * pv, c = qv * pv;
    #pragma unroll
    for (int off = 32; off > 0; off >>= 1) {
        a += __shfl_down(a, off);
        b += __shfl_down(b, off);
        c += __shfl_down(c, off);
    }
    __shared__ float red[3][4];
    const int wv = t >> 6, ln = t & 63;
    if (ln == 0) { red[0][wv] = a; red[1][wv] = b; red[2][wv] = c; }
    __syncthreads();
    const float nq  = red[0][0] + red[0][1] + red[0][2] + red[0][3];
    const float np2 = red[1][0] + red[1][1] + red[1][2] + red[1][3];
    const float qp  = red[2][0] + red[2][1] + red[2][2] + red[2][3];
    const float rq = 1.0f / fmaxf(sqrtf(nq),  1e-12f);
    const float rp = 1.0f / fmaxf(sqrtf(np2), 1e-12f);
    Z[(size_t)row * D_DIM + t]            = __float2bfloat16(qv * rq);
    Z[(size_t)(B_ROWS + row) * D_DIM + t] = __float2bfloat16(pv * rp);
    if (t == 0) pospart[row] = qp * rq * rp;
}

// ---------------------------------------------------------------------------
// Kernel 2: fused S = Z*Z^T + rowsum(exp(2S)), DIRECT-FROM-L2 version.
// Z is 4 MiB -> fully L2-resident per XCD. The LDS staging machinery
// (barriers, vmcnt drains, double-buffers) was re-buffering cache-resident
// data and serializing on it (R0-R3: dur tracked occupancy, not BW).
// Now: each 64-lane WAVE independently computes one 64x64 upper-triangle
// tile, loading MFMA fragments straight from global (16B/lane, immediate
// kk*64B offsets off 8 base pointers). Zero LDS, zero barriers ->
// launch_bounds(256,4) = 128 VGPR cap = 16 waves/CU for pure TLP hiding.
//   A-frag (mfma 16x16x32): lane(m16,quad) <- Z[rowBase+mi*16+m16][kk*32+quad*8..+7]
//   B-frag:                 lane(m16,quad) <- Z[colBase+ni*16+m16][kk*32+quad*8..+7]
// ---------------------------------------------------------------------------
__global__ __launch_bounds__(256, 4) void simexp_direct(
        const __hip_bfloat16* __restrict__ Z, float* __restrict__ denom) {
    const int tid  = threadIdx.x;
    const int lane = tid & 63;
    const int wv   = tid >> 6;            // wave 0..3, fully independent
    const int m16  = lane & 15;
    const int quad = lane >> 4;

    const int gw = blockIdx.x * WPB + wv; // global wave id = tile id, < NPAIR

    // --- triangular decode: gw -> (bi <= bj) over NT64=128 rows ---
    int bi = (int)((257.0 - sqrt(257.0 * 257.0 - 8.0 * (double)gw)) * 0.5);
    // first(b) = b*NT64 - b*(b-1)/2
    while (bi > 0 && (bi * NT64 - bi * (bi - 1) / 2) > gw) --bi;
    while (((bi + 1) * NT64 - (bi + 1) * bi / 2) <= gw) ++bi;
    const int bj = bi + (gw - (bi * NT64 - bi * (bi - 1) / 2));
    const int rowBase = bi * 64;
    const int colBase = bj * 64;

    // --- fragment base pointers: one per mi/ni (imm offset covers kk*64B) ---
    const __hip_bfloat16* abase[4];
    const __hip_bfloat16* bbase[4];
    #pragma unroll
    for (int i = 0; i < 4; ++i) {
        abase[i] = Z + (size_t)(rowBase + i * 16 + m16) * D_DIM + quad * 8;
        bbase[i] = Z + (size_t)(colBase + i * 16 + m16) * D_DIM + quad * 8;
    }

    f32x4 acc[4][4];
    #pragma unroll
    for (int i = 0; i < 4; ++i)
        #pragma unroll
        for (int j = 0; j < 4; ++j) acc[i][j] = (f32x4){0.f, 0.f, 0.f, 0.f};

    // --- K loop: 8 chunks of K=32; loads are L1/L2 hits, hidden by TLP ---
    #pragma unroll
    for (int kk = 0; kk < 8; ++kk) {
        bf16x8 af[4], bfr[4];
        #pragma unroll
        for (int i = 0; i < 4; ++i)
            af[i] = *(const bf16x8*)(abase[i] + kk * 32);
        #pragma unroll
        for (int i = 0; i < 4; ++i)
            bfr[i] = *(const bf16x8*)(bbase[i] + kk * 32);
        #pragma unroll
        for (int mi = 0; mi < 4; ++mi)
            #pragma unroll
            for (int ni = 0; ni < 4; ++ni)
                acc[mi][ni] = __builtin_amdgcn_mfma_f32_16x16x32_bf16(
                    af[mi], bfr[ni], acc[mi][ni], 0, 0, 0);
    }

    // --- epilogue: exp(2s); row partials always, col partials if bi!=bj ---
    // C/D layout: col = lane&15, row = quad*4 + reg  [m89-verified].
    float cs[4] = {0.f, 0.f, 0.f, 0.f};
    float rs[4][4];
    #pragma unroll
    for (int mi = 0; mi < 4; ++mi)
        #pragma unroll
        for (int r = 0; r < 4; ++r) {
            float s = 0.f;
            #pragma unroll
            for (int ni = 0; ni < 4; ++ni) {
                const float e = __expf(2.0f * acc[mi][ni][r]);
                s += e;
                cs[ni] += e;
            }
            rs[mi][r] = s;
        }
    // row sums: reduce across the 16 columns (lanes sharing a quad)
    #pragma unroll
    for (int off = 1; off < 16; off <<= 1)
        #pragma unroll
        for (int mi = 0; mi < 4; ++mi)
            #pragma unroll
            for (int r = 0; r < 4; ++r)
                rs[mi][r] += __shfl_xor(rs[mi][r], off, 64);
    if (m16 == 0) {
        #pragma unroll
        for (int mi = 0; mi < 4; ++mi)
            #pragma unroll
            for (int r = 0; r < 4; ++r)
                atomicAdd(&denom[rowBase + mi * 16 + quad * 4 + r], rs[mi][r]);
    }
    // col sums: reduce across the 4 quads (rows) -> symmetric contribution
    if (bi != bj) {
        #pragma unroll
        for (int off = 16; off < 64; off <<= 1)
            #pragma unroll
            for (int ni = 0; ni < 4; ++ni)
                cs[ni] += __shfl_xor(cs[ni], off, 64);
        if (lane < 16) {
            #pragma unroll
            for (int ni = 0; ni < 4; ++ni)
                atomicAdd(&denom[colBase + ni * 16 + m16], cs[ni]);
        }
    }
}

// ---------------------------------------------------------------------------
// Kernel 3: loss = (sum_i log(denom_i - e^2) - 4*sum_i pospart_i) / 8192
// ---------------------------------------------------------------------------
__global__ __launch_bounds__(256) void finalize_kernel(
        const float* __restrict__ denom, const float* __restrict__ pospart,
        float* __restrict__ out) {
    const int t = threadIdx.x;
    float s = 0.f;
    for (int i = t; i < N_TOT; i += 256) s += logf(denom[i] - E2);
    float pp = 0.f;
    for (int i = t; i < B_ROWS; i += 256) pp += pospart[i];
    s -= 4.0f * pp;
    #pragma unroll
    for (int off = 32; off > 0; off >>= 1) s += __shfl_down(s, off);
    __shared__ float red[4];
    if ((t & 63) == 0) red[t >> 6] = s;
    __syncthreads();
    if (t == 0)
        out[0] = (red[0] + red[1] + red[2] + red[3]) / (float)N_TOT;
}

extern "C" void kernel_launch(void* const* d_in, const int* in_sizes, int n_in,
                              void* d_out, int out_size, void* d_ws, size_t ws_size,
                              hipStream_t stream) {
    const float* q = (const float*)d_in[0];
    const float* p = (const float*)d_in[1];
    // d_in[2] (neg) is normalized in the original but never used in the loss.
    float* out = (float*)d_out;

    // Workspace: Z bf16 [8192*256] (4 MiB) | denom f32 [8192] | pospart f32 [4096]
    __hip_bfloat16* Z = (__hip_bfloat16*)d_ws;
    float* denom   = (float*)((char*)d_ws + (size_t)N_TOT * D_DIM * sizeof(__hip_bfloat16));
    float* pospart = denom + N_TOT;

    hipLaunchKernelGGL(norm_kernel, dim3(B_ROWS), dim3(256), 0, stream,
                       q, p, Z, pospart, denom);
    hipLaunchKernelGGL(simexp_direct, dim3(NBLK2), dim3(256), 0, stream, Z, denom);
    hipLaunchKernelGGL(finalize_kernel, dim3(1), dim3(256), 0, stream,
                       denom, pospart, out);
}

// Round 7
// 148.247 us; speedup vs baseline: 1.1435x; 1.1435x over previous
//
#include <hip/hip_runtime.h>
#include <hip/hip_bf16.h>
#include <math.h>

#define B_ROWS 4096
#define D_DIM  256
#define N_TOT  8192            // 2B
#define E2     7.38905609893065f   // exp(2) = diagonal term of the row sum
#define NTILE  64              // 8192 / 128
#define NBLK   (NTILE * (NTILE + 1) / 2)   // 2080 upper-triangle tile pairs

typedef __attribute__((ext_vector_type(4))) float f32x4;
typedef __attribute__((ext_vector_type(8))) short bf16x8;   // 8 bf16 in 4 VGPRs

__device__ __forceinline__ void async_copy16(const void* gptr, void* lptr) {
    // NOTE: lptr is the WAVE-UNIFORM base; HW scatters lane*16 itself.
    __builtin_amdgcn_global_load_lds(
        (const __attribute__((address_space(1))) unsigned int*)gptr,
        (__attribute__((address_space(3))) unsigned int*)lptr,
        16 /*bytes*/, 0 /*offset*/, 0 /*aux*/);
}

// ---------------------------------------------------------------------------
// Kernel 1: per-row L2-normalize query & pos -> bf16 Z[8192][256]; per-row
// positive dot to pospart[row]. Blocks 0..31 also zero denom[8192].
// (Exact R0 version — proven across three passing runs.)
// ---------------------------------------------------------------------------
__global__ __launch_bounds__(256) void norm_kernel(
        const float* __restrict__ q, const float* __restrict__ p,
        __hip_bfloat16* __restrict__ Z, float* __restrict__ pospart,
        float* __restrict__ denom) {
    const int row = blockIdx.x;          // 0..4095
    const int t   = threadIdx.x;         // 0..255
    if (row < 32) denom[row * 256 + t] = 0.0f;
    const float qv = q[row * D_DIM + t];
    const float pv = p[row * D_DIM + t];
    float a = qv * qv, b = pv * pv, c = qv * pv;
    #pragma unroll
    for (int off = 32; off > 0; off >>= 1) {
        a += __shfl_down(a, off);
        b += __shfl_down(b, off);
        c += __shfl_down(c, off);
    }
    __shared__ float red[3][4];
    const int wv = t >> 6, ln = t & 63;
    if (ln == 0) { red[0][wv] = a; red[1][wv] = b; red[2][wv] = c; }
    __syncthreads();
    const float nq  = red[0][0] + red[0][1] + red[0][2] + red[0][3];
    const float np2 = red[1][0] + red[1][1] + red[1][2] + red[1][3];
    const float qp  = red[2][0] + red[2][1] + red[2][2] + red[2][3];
    const float rq = 1.0f / fmaxf(sqrtf(nq),  1e-12f);
    const float rp = 1.0f / fmaxf(sqrtf(np2), 1e-12f);
    Z[(size_t)row * D_DIM + t]            = __float2bfloat16(qv * rq);
    Z[(size_t)(B_ROWS + row) * D_DIM + t] = __float2bfloat16(pv * rp);
    if (t == 0) pospart[row] = qp * rq * rp;
}

// ---------------------------------------------------------------------------
// Kernel 2: fused S = Z*Z^T, upper-triangle tile pairs (symmetry), with
// epilogue rowsum += sum_j exp(2*S). R0's proven structure (128x128 tile,
// BK=64, single-buffered 32 KB LDS, 2 barriers/kt) with ONE change:
// 8 waves/block (512 thr), each wave owns a 64x32 sub-tile (wave grid 2Mx4N).
//   - acc shrinks 64->32 AGPR, frags 32->24: natural footprint ~100 unified
//     regs -> 5 waves/SIMD -> 2 blocks/CU = 16 waves/CU resident (2x R0's 8)
//     WITHOUT any forced launch_bounds cap (the R5/R6 (256,4) bound is the
//     prime suspect for the compile-time blowup that killed those runs).
//   - per-block MFMA count unchanged; staging = 2 A + 2 B instrs per wave.
// LDS 32 KB x 2 blocks = 64 KB, threads 1024/CU: both fit.
// ---------------------------------------------------------------------------
__global__ __launch_bounds__(512) void simexp_gemm(
        const __hip_bfloat16* __restrict__ Z, float* __restrict__ denom) {
    __shared__ __hip_bfloat16 As[128 * 64];   // 16 KB, row stride 128 B
    __shared__ __hip_bfloat16 Bs[128 * 64];   // 16 KB
    const int tid    = threadIdx.x;
    const int lane   = tid & 63;
    const int wv     = tid >> 6;      // wave id 0..7
    const int wave_m = wv >> 2;       // 0..1  (row half: 64 rows)
    const int wave_n = wv & 3;        // 0..3  (col quarter: 32 cols)
    const int m16    = lane & 15;
    const int quad   = lane >> 4;

    // --- triangular decode: bid -> (bi <= bj)  (R0-proven) ---
    const int bid = blockIdx.x;
    int bi = (int)((129.0 - sqrt(129.0 * 129.0 - 8.0 * (double)bid)) * 0.5);
    while (bi > 0 && (bi * NTILE - bi * (bi - 1) / 2) > bid) --bi;
    while (((bi + 1) * NTILE - (bi + 1) * bi / 2) <= bid) ++bi;
    const int bj = bi + (bid - (bi * NTILE - bi * (bi - 1) / 2));
    const int rowBase = bi * 128;
    const int colBase = bj * 128;

    f32x4 acc[4][2];
    #pragma unroll
    for (int i = 0; i < 4; ++i)
        #pragma unroll
        for (int j = 0; j < 2; ++j) acc[i][j] = (f32x4){0.f, 0.f, 0.f, 0.f};

    // staging geometry: one instr = 64 lanes x 16B = 8 rows of 128B.
    // 8 waves x 2 instrs per matrix cover 128 rows. lane l -> local row
    // (l>>3), chunk slot (l&7); LDS chunk c of row r holds global chunk
    // c ^ (r&7) (xor involution). u32 byte offsets vs uniform Z base.
    const int lrow = lane >> 3;
    const int lchk = lane & 7;
    unsigned int aoff[2], boff[2];
    #pragma unroll
    for (int pp = 0; pp < 2; ++pp) {
        const int r = wv * 16 + pp * 8 + lrow;          // local row 0..127
        const int g = lchk ^ (r & 7);                   // swizzled global chunk
        aoff[pp] = (unsigned int)((rowBase + r) * 512 + g * 16);
        boff[pp] = (unsigned int)((colBase + r) * 512 + g * 16);
    }

    for (int kt = 0; kt < 4; ++kt) {
        __syncthreads();   // previous iter's LDS reads done before overwrite
        #pragma unroll
        for (int pp = 0; pp < 2; ++pp) {
            async_copy16((const char*)Z + aoff[pp],
                         (char*)As + (wv * 16 + pp * 8) * 128);
            async_copy16((const char*)Z + boff[pp],
                         (char*)Bs + (wv * 16 + pp * 8) * 128);
            aoff[pp] += 128;   // next K-chunk (64 elems = 128 B)
            boff[pp] += 128;
        }
        __syncthreads();   // drains vmcnt: staging complete

        #pragma unroll
        for (int kt2 = 0; kt2 < 2; ++kt2) {
            const int sw = (kt2 * 4 + quad) ^ (m16 & 7);  // swizzled chunk
            const unsigned int abase =
                (unsigned int)((wave_m * 64 + m16) * 128 + sw * 16);
            const unsigned int bbase =
                (unsigned int)((wave_n * 32 + m16) * 128 + sw * 16);
            bf16x8 af[4], bfr[2];
            #pragma unroll
            for (int mi = 0; mi < 4; ++mi)
                af[mi] = *(const bf16x8*)((const char*)As + abase + mi * 2048);
            #pragma unroll
            for (int ni = 0; ni < 2; ++ni)
                bfr[ni] = *(const bf16x8*)((const char*)Bs + bbase + ni * 2048);
            #pragma unroll
            for (int mi = 0; mi < 4; ++mi)
                #pragma unroll
                for (int ni = 0; ni < 2; ++ni)
                    acc[mi][ni] = __builtin_amdgcn_mfma_f32_16x16x32_bf16(
                        af[mi], bfr[ni], acc[mi][ni], 0, 0, 0);
        }
    }

    // --- epilogue: exp(2s) once; accumulate row partials and col partials ---
    // C/D layout: col = lane&15, row = quad*4 + reg  [m89-verified].
    float cs[2] = {0.f, 0.f};
    float rs[4][4];
    #pragma unroll
    for (int mi = 0; mi < 4; ++mi)
        #pragma unroll
        for (int r = 0; r < 4; ++r) {
            float s = 0.f;
            #pragma unroll
            for (int ni = 0; ni < 2; ++ni) {
                const float e = __expf(2.0f * acc[mi][ni][r]);
                s += e;
                cs[ni] += e;
            }
            rs[mi][r] = s;
        }
    // row sums: reduce across the 16 columns (lanes sharing a quad)
    #pragma unroll
    for (int off = 1; off < 16; off <<= 1)
        #pragma unroll
        for (int mi = 0; mi < 4; ++mi)
            #pragma unroll
            for (int r = 0; r < 4; ++r)
                rs[mi][r] += __shfl_xor(rs[mi][r], off, 64);
    if (m16 == 0) {
        #pragma unroll
        for (int mi = 0; mi < 4; ++mi)
            #pragma unroll
            for (int r = 0; r < 4; ++r)
                atomicAdd(&denom[rowBase + wave_m * 64 + mi * 16 + quad * 4 + r],
                          rs[mi][r]);
    }
    // col sums: reduce across the 4 quads (rows) -> symmetric contribution
    if (bi != bj) {
        #pragma unroll
        for (int off = 16; off < 64; off <<= 1)
            #pragma unroll
            for (int ni = 0; ni < 2; ++ni)
                cs[ni] += __shfl_xor(cs[ni], off, 64);
        if (lane < 16) {
            #pragma unroll
            for (int ni = 0; ni < 2; ++ni)
                atomicAdd(&denom[colBase + wave_n * 32 + ni * 16 + m16], cs[ni]);
        }
    }
}

// ---------------------------------------------------------------------------
// Kernel 3: loss = (sum_i log(denom_i - e^2) - 4*sum_i pospart_i) / 8192
// ---------------------------------------------------------------------------
__global__ __launch_bounds__(256) void finalize_kernel(
        const float* __restrict__ denom, const float* __restrict__ pospart,
        float* __restrict__ out) {
    const int t = threadIdx.x;
    float s = 0.f;
    for (int i = t; i < N_TOT; i += 256) s += logf(denom[i] - E2);
    float pp = 0.f;
    for (int i = t; i < B_ROWS; i += 256) pp += pospart[i];
    s -= 4.0f * pp;
    #pragma unroll
    for (int off = 32; off > 0; off >>= 1) s += __shfl_down(s, off);
    __shared__ float red[4];
    if ((t & 63) == 0) red[t >> 6] = s;
    __syncthreads();
    if (t == 0)
        out[0] = (red[0] + red[1] + red[2] + red[3]) / (float)N_TOT;
}

extern "C" void kernel_launch(void* const* d_in, const int* in_sizes, int n_in,
                              void* d_out, int out_size, void* d_ws, size_t ws_size,
                              hipStream_t stream) {
    const float* q = (const float*)d_in[0];
    const float* p = (const float*)d_in[1];
    // d_in[2] (neg) is normalized in the original but never used in the loss.
    float* out = (float*)d_out;

    // Workspace: Z bf16 [8192*256] (4 MiB) | denom f32 [8192] | pospart f32 [4096]
    __hip_bfloat16* Z = (__hip_bfloat16*)d_ws;
    float* denom   = (float*)((char*)d_ws + (size_t)N_TOT * D_DIM * sizeof(__hip_bfloat16));
    float* pospart = denom + N_TOT;

    hipLaunchKernelGGL(norm_kernel, dim3(B_ROWS), dim3(256), 0, stream,
                       q, p, Z, pospart, denom);
    hipLaunchKernelGGL(simexp_gemm, dim3(NBLK), dim3(512), 0, stream, Z, denom);
    hipLaunchKernelGGL(finalize_kernel, dim3(1), dim3(256), 0, stream,
                       denom, pospart, out);
}

// Round 8
// 121.110 us; speedup vs baseline: 1.3997x; 1.2241x over previous
//
#include <hip/hip_runtime.h>
#include <hip/hip_bf16.h>
#include <math.h>

#define B_ROWS 4096
#define D_DIM  256
#define N_TOT  8192            // 2B
#define E2     7.38905609893065f   // exp(2) = diagonal term of the row sum
#define NTILE  64              // 8192 / 128
#define NBLK   (NTILE * (NTILE + 1) / 2)   // 2080 upper-triangle tile pairs
#define NSLOT  128             // 2 sub-slots per tile-row (wave_n / wave_m split)

typedef __attribute__((ext_vector_type(4))) float f32x4;
typedef __attribute__((ext_vector_type(8))) short bf16x8;   // 8 bf16 in 4 VGPRs

__device__ __forceinline__ void async_copy16(const void* gptr, void* lptr) {
    // NOTE: lptr is the WAVE-UNIFORM base; HW scatters lane*16 itself.
    __builtin_amdgcn_global_load_lds(
        (const __attribute__((address_space(1))) unsigned int*)gptr,
        (__attribute__((address_space(3))) unsigned int*)lptr,
        16 /*bytes*/, 0 /*offset*/, 0 /*aux*/);
}

// ---------------------------------------------------------------------------
// Kernel 1: per-row L2-normalize query & pos -> bf16 Z[8192][256]; per-row
// positive dot to pospart[row]. (R0-proven; denom zeroing removed — the
// partials buffer is written exactly once per slot, no init needed.)
// ---------------------------------------------------------------------------
__global__ __launch_bounds__(256) void norm_kernel(
        const float* __restrict__ q, const float* __restrict__ p,
        __hip_bfloat16* __restrict__ Z, float* __restrict__ pospart) {
    const int row = blockIdx.x;          // 0..4095
    const int t   = threadIdx.x;         // 0..255
    const float qv = q[row * D_DIM + t];
    const float pv = p[row * D_DIM + t];
    float a = qv * qv, b = pv * pv, c = qv * pv;
    #pragma unroll
    for (int off = 32; off > 0; off >>= 1) {
        a += __shfl_down(a, off);
        b += __shfl_down(b, off);
        c += __shfl_down(c, off);
    }
    __shared__ float red[3][4];
    const int wv = t >> 6, ln = t & 63;
    if (ln == 0) { red[0][wv] = a; red[1][wv] = b; red[2][wv] = c; }
    __syncthreads();
    const float nq  = red[0][0] + red[0][1] + red[0][2] + red[0][3];
    const float np2 = red[1][0] + red[1][1] + red[1][2] + red[1][3];
    const float qp  = red[2][0] + red[2][1] + red[2][2] + red[2][3];
    const float rq = 1.0f / fmaxf(sqrtf(nq),  1e-12f);
    const float rp = 1.0f / fmaxf(sqrtf(np2), 1e-12f);
    Z[(size_t)row * D_DIM + t]            = __float2bfloat16(qv * rq);
    Z[(size_t)(B_ROWS + row) * D_DIM + t] = __float2bfloat16(pv * rp);
    if (t == 0) pospart[row] = qp * rq * rp;
}

// ---------------------------------------------------------------------------
// Kernel 2: fused S = Z*Z^T, upper-triangle tile pairs (symmetry), with
// epilogue rowsum partials of exp(2*S). EXACT R0 GEMM structure (128x128
// tile, BK=64, 4 waves, single-buffered 32 KB LDS, 2 barriers/kt — best
// measured 47 us) + u32-offset staging (ran clean in R7).
// THIS ROUND'S ONE CHANGE: the ~512 contended device-scope atomicAdds per
// block (present in EVERY prior version; dur tracked atomic count R0/R3/R7)
// are replaced by collision-free plain stores into bufP[128][8192]:
//   row-partials of block (bi,bj) -> slot 2*bj+wave_n, rows of tile bi
//   col-partials of block (bi,bj) -> slot 2*bi+wave_m, cols of tile bj
// For slot 2t+u of tile b exactly one of (b,t)[row] / (t,b)[col] exists
// (diagonal writes row slots only) => every slot written exactly once.
// A 32-block reduce kernel folds the 128 partials/row into denom.
// ---------------------------------------------------------------------------
__global__ __launch_bounds__(256) void simexp_gemm(
        const __hip_bfloat16* __restrict__ Z, float* __restrict__ bufP) {
    __shared__ __hip_bfloat16 As[128 * 64];   // 16 KB, row stride 128 B
    __shared__ __hip_bfloat16 Bs[128 * 64];   // 16 KB
    const int tid    = threadIdx.x;
    const int lane   = tid & 63;
    const int wv     = tid >> 6;      // wave id 0..3
    const int wave_m = wv >> 1;       // 0..1  (row half)
    const int wave_n = wv & 1;        // 0..1  (col half)
    const int m16    = lane & 15;
    const int quad   = lane >> 4;

    // --- triangular decode: bid -> (bi <= bj) ---
    const int bid = blockIdx.x;
    int bi = (int)((129.0 - sqrt(129.0 * 129.0 - 8.0 * (double)bid)) * 0.5);
    while (bi > 0 && (bi * NTILE - bi * (bi - 1) / 2) > bid) --bi;
    while (((bi + 1) * NTILE - (bi + 1) * bi / 2) <= bid) ++bi;
    const int bj = bi + (bid - (bi * NTILE - bi * (bi - 1) / 2));
    const int rowBase = bi * 128;
    const int colBase = bj * 128;

    f32x4 acc[4][4];
    #pragma unroll
    for (int i = 0; i < 4; ++i)
        #pragma unroll
        for (int j = 0; j < 4; ++j) acc[i][j] = (f32x4){0.f, 0.f, 0.f, 0.f};

    // staging geometry: one instr = 64 lanes x 16B = 8 rows of 128B.
    // lane l -> local row (l>>3), chunk slot (l&7); LDS chunk c of row r
    // holds global chunk c ^ (r&7) (xor involution). u32 byte offsets.
    const int lrow = lane >> 3;
    const int lchk = lane & 7;
    unsigned int aoff[4], boff[4];
    #pragma unroll
    for (int pp = 0; pp < 4; ++pp) {
        const int r = wv * 32 + pp * 8 + lrow;          // local row 0..127
        const int g = lchk ^ (r & 7);                   // swizzled global chunk
        aoff[pp] = (unsigned int)((rowBase + r) * 512 + g * 16);
        boff[pp] = (unsigned int)((colBase + r) * 512 + g * 16);
    }

    for (int kt = 0; kt < 4; ++kt) {
        __syncthreads();   // previous iter's LDS reads done before overwrite
        #pragma unroll
        for (int pp = 0; pp < 4; ++pp) {
            async_copy16((const char*)Z + aoff[pp],
                         (char*)As + (wv * 32 + pp * 8) * 128);
            async_copy16((const char*)Z + boff[pp],
                         (char*)Bs + (wv * 32 + pp * 8) * 128);
            aoff[pp] += 128;   // next K-chunk (64 elems = 128 B)
            boff[pp] += 128;
        }
        __syncthreads();   // drains vmcnt: staging complete

        #pragma unroll
        for (int kt2 = 0; kt2 < 2; ++kt2) {
            const int sw = (kt2 * 4 + quad) ^ (m16 & 7);  // swizzled chunk
            const unsigned int abase =
                (unsigned int)((wave_m * 64 + m16) * 128 + sw * 16);
            const unsigned int bbase =
                (unsigned int)((wave_n * 64 + m16) * 128 + sw * 16);
            bf16x8 af[4], bfr[4];
            #pragma unroll
            for (int mi = 0; mi < 4; ++mi)
                af[mi] = *(const bf16x8*)((const char*)As + abase + mi * 2048);
            #pragma unroll
            for (int ni = 0; ni < 4; ++ni)
                bfr[ni] = *(const bf16x8*)((const char*)Bs + bbase + ni * 2048);
            #pragma unroll
            for (int mi = 0; mi < 4; ++mi)
                #pragma unroll
                for (int ni = 0; ni < 4; ++ni)
                    acc[mi][ni] = __builtin_amdgcn_mfma_f32_16x16x32_bf16(
                        af[mi], bfr[ni], acc[mi][ni], 0, 0, 0);
        }
    }

    // --- epilogue: exp(2s) once; row partials and col partials ---
    // C/D layout: col = lane&15, row = quad*4 + reg  [m89-verified].
    float cs[4] = {0.f, 0.f, 0.f, 0.f};
    float rs[4][4];
    #pragma unroll
    for (int mi = 0; mi < 4; ++mi)
        #pragma unroll
        for (int r = 0; r < 4; ++r) {
            float s = 0.f;
            #pragma unroll
            for (int ni = 0; ni < 4; ++ni) {
                const float e = __expf(2.0f * acc[mi][ni][r]);
                s += e;
                cs[ni] += e;
            }
            rs[mi][r] = s;
        }
    // row sums: reduce across the 16 columns (lanes sharing a quad)
    #pragma unroll
    for (int off = 1; off < 16; off <<= 1)
        #pragma unroll
        for (int mi = 0; mi < 4; ++mi)
            #pragma unroll
            for (int r = 0; r < 4; ++r)
                rs[mi][r] += __shfl_xor(rs[mi][r], off, 64);
    if (m16 == 0) {
        float* dst = bufP + (size_t)(2 * bj + wave_n) * N_TOT + rowBase;
        #pragma unroll
        for (int mi = 0; mi < 4; ++mi)
            #pragma unroll
            for (int r = 0; r < 4; ++r)
                dst[wave_m * 64 + mi * 16 + quad * 4 + r] = rs[mi][r];
    }
    // col sums: reduce across the 4 quads (rows) -> symmetric contribution
    if (bi != bj) {
        #pragma unroll
        for (int off = 16; off < 64; off <<= 1)
            #pragma unroll
            for (int ni = 0; ni < 4; ++ni)
                cs[ni] += __shfl_xor(cs[ni], off, 64);
        if (lane < 16) {
            float* dst = bufP + (size_t)(2 * bi + wave_m) * N_TOT + colBase;
            #pragma unroll
            for (int ni = 0; ni < 4; ++ni)
                dst[wave_n * 64 + ni * 16 + m16] = cs[ni];
        }
    }
}

// ---------------------------------------------------------------------------
// Kernel 2b: denom[r] = sum over the 128 partial slots. 4 MB of L2-resident
// reads, coalesced per slot iteration; deterministic order.
// ---------------------------------------------------------------------------
__global__ __launch_bounds__(256) void reduce_kernel(
        const float* __restrict__ bufP, float* __restrict__ denom) {
    const int r = blockIdx.x * 256 + threadIdx.x;   // 0..8191
    float s0 = 0.f, s1 = 0.f, s2 = 0.f, s3 = 0.f;
    #pragma unroll 4
    for (int t = 0; t < NSLOT; t += 4) {
        s0 += bufP[(size_t)(t + 0) * N_TOT + r];
        s1 += bufP[(size_t)(t + 1) * N_TOT + r];
        s2 += bufP[(size_t)(t + 2) * N_TOT + r];
        s3 += bufP[(size_t)(t + 3) * N_TOT + r];
    }
    denom[r] = (s0 + s1) + (s2 + s3);
}

// ---------------------------------------------------------------------------
// Kernel 3: loss = (sum_i log(denom_i - e^2) - 4*sum_i pospart_i) / 8192
// ---------------------------------------------------------------------------
__global__ __launch_bounds__(256) void finalize_kernel(
        const float* __restrict__ denom, const float* __restrict__ pospart,
        float* __restrict__ out) {
    const int t = threadIdx.x;
    float s = 0.f;
    for (int i = t; i < N_TOT; i += 256) s += logf(denom[i] - E2);
    float pp = 0.f;
    for (int i = t; i < B_ROWS; i += 256) pp += pospart[i];
    s -= 4.0f * pp;
    #pragma unroll
    for (int off = 32; off > 0; off >>= 1) s += __shfl_down(s, off);
    __shared__ float red[4];
    if ((t & 63) == 0) red[t >> 6] = s;
    __syncthreads();
    if (t == 0)
        out[0] = (red[0] + red[1] + red[2] + red[3]) / (float)N_TOT;
}

extern "C" void kernel_launch(void* const* d_in, const int* in_sizes, int n_in,
                              void* d_out, int out_size, void* d_ws, size_t ws_size,
                              hipStream_t stream) {
    const float* q = (const float*)d_in[0];
    const float* p = (const float*)d_in[1];
    // d_in[2] (neg) is normalized in the original but never used in the loss.
    float* out = (float*)d_out;

    // Workspace layout:
    //   Z     bf16 [8192*256]   @ 0        (4 MiB)
    //   bufP  f32  [128*8192]   @ 4 MiB    (4 MiB)  exp-sum partials
    //   denom f32  [8192]       @ 8 MiB
    //   pospart f32 [4096]      after denom
    __hip_bfloat16* Z = (__hip_bfloat16*)d_ws;
    float* bufP    = (float*)((char*)d_ws + (size_t)N_TOT * D_DIM * sizeof(__hip_bfloat16));
    float* denom   = bufP + (size_t)NSLOT * N_TOT;
    float* pospart = denom + N_TOT;

    hipLaunchKernelGGL(norm_kernel, dim3(B_ROWS), dim3(256), 0, stream,
                       q, p, Z, pospart);
    hipLaunchKernelGGL(simexp_gemm, dim3(NBLK), dim3(256), 0, stream, Z, bufP);
    hipLaunchKernelGGL(reduce_kernel, dim3(N_TOT / 256), dim3(256), 0, stream,
                       bufP, denom);
    hipLaunchKernelGGL(finalize_kernel, dim3(1), dim3(256), 0, stream,
                       denom, pospart, out);
}

// Round 9
// 105.974 us; speedup vs baseline: 1.5996x; 1.1428x over previous
//
#include <hip/hip_runtime.h>
#include <hip/hip_bf16.h>
#include <math.h>

#define B_ROWS 4096
#define D_DIM  256
#define N_TOT  8192            // 2B
#define E2     7.38905609893065f   // exp(2) = diagonal term of the row sum
#define NTILE  64              // 8192 / 128
#define NBLK   (NTILE * (NTILE + 1) / 2)   // 2080 upper-triangle tile pairs
#define NSLOT  128             // 2 sub-slots per tile-row (wave_n / wave_m split)

typedef __attribute__((ext_vector_type(4))) float f32x4;
typedef __attribute__((ext_vector_type(8))) short bf16x8;   // 8 bf16 in 4 VGPRs

__device__ __forceinline__ void async_copy16(const void* gptr, void* lptr) {
    // NOTE: lptr is the WAVE-UNIFORM base; HW scatters lane*16 itself.
    __builtin_amdgcn_global_load_lds(
        (const __attribute__((address_space(1))) unsigned int*)gptr,
        (__attribute__((address_space(3))) unsigned int*)lptr,
        16 /*bytes*/, 0 /*offset*/, 0 /*aux*/);
}

__device__ __forceinline__ unsigned short bf16_bits(float x) {
    __hip_bfloat16 h = __float2bfloat16(x);
    return *reinterpret_cast<unsigned short*>(&h);
}

// ---------------------------------------------------------------------------
// Kernel 1: wave-per-row L2-normalize query & pos -> bf16 Z[8192][256]; per-
// row positive dot to pospart[row]. Vectorized f32x4 loads, pure shfl_xor
// reduce, no LDS, no barrier. Grid 1024 x 256 (4 rows/block, 1 wave/row).
// Replaces the scalar-load + block-barrier version (Guideline 13: scalar
// loads ~2-2.5x slower; per-row __syncthreads latency).
// ---------------------------------------------------------------------------
__global__ __launch_bounds__(256) void norm_kernel(
        const float* __restrict__ q, const float* __restrict__ p,
        __hip_bfloat16* __restrict__ Z, float* __restrict__ pospart) {
    const int t    = threadIdx.x;
    const int wv   = t >> 6;
    const int lane = t & 63;
    const int row  = blockIdx.x * 4 + wv;        // 0..4095

    const f32x4 qv = *(const f32x4*)(q + (size_t)row * D_DIM + lane * 4);
    const f32x4 pv = *(const f32x4*)(p + (size_t)row * D_DIM + lane * 4);
    float a = qv[0]*qv[0] + qv[1]*qv[1] + qv[2]*qv[2] + qv[3]*qv[3];
    float b = pv[0]*pv[0] + pv[1]*pv[1] + pv[2]*pv[2] + pv[3]*pv[3];
    float c = qv[0]*pv[0] + qv[1]*pv[1] + qv[2]*pv[2] + qv[3]*pv[3];
    #pragma unroll
    for (int off = 32; off > 0; off >>= 1) {
        a += __shfl_xor(a, off);
        b += __shfl_xor(b, off);
        c += __shfl_xor(c, off);
    }
    const float rq = 1.0f / fmaxf(sqrtf(a), 1e-12f);
    const float rp = 1.0f / fmaxf(sqrtf(b), 1e-12f);

    ushort4 zq, zp;
    zq.x = bf16_bits(qv[0] * rq); zq.y = bf16_bits(qv[1] * rq);
    zq.z = bf16_bits(qv[2] * rq); zq.w = bf16_bits(qv[3] * rq);
    zp.x = bf16_bits(pv[0] * rp); zp.y = bf16_bits(pv[1] * rp);
    zp.z = bf16_bits(pv[2] * rp); zp.w = bf16_bits(pv[3] * rp);
    *(ushort4*)(Z + (size_t)row * D_DIM + lane * 4)            = zq;
    *(ushort4*)(Z + (size_t)(B_ROWS + row) * D_DIM + lane * 4) = zp;
    if (lane == 0) pospart[row] = c * rq * rp;
}

// ---------------------------------------------------------------------------
// Kernel 2: fused S = Z*Z^T, upper-triangle tile pairs (symmetry), epilogue
// rowsum partials of exp(2*S) via collision-free plain stores (R8-proven,
// frozen this round). 128x128 tile, BK=64, 4 waves, single-buffered 32 KB
// LDS, 2 barriers/kt, u32-offset staging, XOR source swizzle.
//   row-partials of block (bi,bj) -> slot 2*bj+wave_n, rows of tile bi
//   col-partials of block (bi,bj) -> slot 2*bi+wave_m, cols of tile bj
// Every slot of bufP[128][8192] written exactly once (diagonal: row slots
// only), so no init and no atomics.
// ---------------------------------------------------------------------------
__global__ __launch_bounds__(256) void simexp_gemm(
        const __hip_bfloat16* __restrict__ Z, float* __restrict__ bufP) {
    __shared__ __hip_bfloat16 As[128 * 64];   // 16 KB, row stride 128 B
    __shared__ __hip_bfloat16 Bs[128 * 64];   // 16 KB
    const int tid    = threadIdx.x;
    const int lane   = tid & 63;
    const int wv     = tid >> 6;      // wave id 0..3
    const int wave_m = wv >> 1;       // 0..1  (row half)
    const int wave_n = wv & 1;        // 0..1  (col half)
    const int m16    = lane & 15;
    const int quad   = lane >> 4;

    // --- triangular decode: bid -> (bi <= bj) ---
    const int bid = blockIdx.x;
    int bi = (int)((129.0 - sqrt(129.0 * 129.0 - 8.0 * (double)bid)) * 0.5);
    while (bi > 0 && (bi * NTILE - bi * (bi - 1) / 2) > bid) --bi;
    while (((bi + 1) * NTILE - (bi + 1) * bi / 2) <= bid) ++bi;
    const int bj = bi + (bid - (bi * NTILE - bi * (bi - 1) / 2));
    const int rowBase = bi * 128;
    const int colBase = bj * 128;

    f32x4 acc[4][4];
    #pragma unroll
    for (int i = 0; i < 4; ++i)
        #pragma unroll
        for (int j = 0; j < 4; ++j) acc[i][j] = (f32x4){0.f, 0.f, 0.f, 0.f};

    // staging geometry: one instr = 64 lanes x 16B = 8 rows of 128B.
    // lane l -> local row (l>>3), chunk slot (l&7); LDS chunk c of row r
    // holds global chunk c ^ (r&7) (xor involution). u32 byte offsets.
    const int lrow = lane >> 3;
    const int lchk = lane & 7;
    unsigned int aoff[4], boff[4];
    #pragma unroll
    for (int pp = 0; pp < 4; ++pp) {
        const int r = wv * 32 + pp * 8 + lrow;          // local row 0..127
        const int g = lchk ^ (r & 7);                   // swizzled global chunk
        aoff[pp] = (unsigned int)((rowBase + r) * 512 + g * 16);
        boff[pp] = (unsigned int)((colBase + r) * 512 + g * 16);
    }

    for (int kt = 0; kt < 4; ++kt) {
        __syncthreads();   // previous iter's LDS reads done before overwrite
        #pragma unroll
        for (int pp = 0; pp < 4; ++pp) {
            async_copy16((const char*)Z + aoff[pp],
                         (char*)As + (wv * 32 + pp * 8) * 128);
            async_copy16((const char*)Z + boff[pp],
                         (char*)Bs + (wv * 32 + pp * 8) * 128);
            aoff[pp] += 128;   // next K-chunk (64 elems = 128 B)
            boff[pp] += 128;
        }
        __syncthreads();   // drains vmcnt: staging complete

        #pragma unroll
        for (int kt2 = 0; kt2 < 2; ++kt2) {
            const int sw = (kt2 * 4 + quad) ^ (m16 & 7);  // swizzled chunk
            const unsigned int abase =
                (unsigned int)((wave_m * 64 + m16) * 128 + sw * 16);
            const unsigned int bbase =
                (unsigned int)((wave_n * 64 + m16) * 128 + sw * 16);
            bf16x8 af[4], bfr[4];
            #pragma unroll
            for (int mi = 0; mi < 4; ++mi)
                af[mi] = *(const bf16x8*)((const char*)As + abase + mi * 2048);
            #pragma unroll
            for (int ni = 0; ni < 4; ++ni)
                bfr[ni] = *(const bf16x8*)((const char*)Bs + bbase + ni * 2048);
            #pragma unroll
            for (int mi = 0; mi < 4; ++mi)
                #pragma unroll
                for (int ni = 0; ni < 4; ++ni)
                    acc[mi][ni] = __builtin_amdgcn_mfma_f32_16x16x32_bf16(
                        af[mi], bfr[ni], acc[mi][ni], 0, 0, 0);
        }
    }

    // --- epilogue: exp(2s) once; row partials and col partials ---
    // C/D layout: col = lane&15, row = quad*4 + reg  [m89-verified].
    float cs[4] = {0.f, 0.f, 0.f, 0.f};
    float rs[4][4];
    #pragma unroll
    for (int mi = 0; mi < 4; ++mi)
        #pragma unroll
        for (int r = 0; r < 4; ++r) {
            float s = 0.f;
            #pragma unroll
            for (int ni = 0; ni < 4; ++ni) {
                const float e = __expf(2.0f * acc[mi][ni][r]);
                s += e;
                cs[ni] += e;
            }
            rs[mi][r] = s;
        }
    // row sums: reduce across the 16 columns (lanes sharing a quad)
    #pragma unroll
    for (int off = 1; off < 16; off <<= 1)
        #pragma unroll
        for (int mi = 0; mi < 4; ++mi)
            #pragma unroll
            for (int r = 0; r < 4; ++r)
                rs[mi][r] += __shfl_xor(rs[mi][r], off, 64);
    if (m16 == 0) {
        float* dst = bufP + (size_t)(2 * bj + wave_n) * N_TOT + rowBase;
        #pragma unroll
        for (int mi = 0; mi < 4; ++mi)
            #pragma unroll
            for (int r = 0; r < 4; ++r)
                dst[wave_m * 64 + mi * 16 + quad * 4 + r] = rs[mi][r];
    }
    // col sums: reduce across the 4 quads (rows) -> symmetric contribution
    if (bi != bj) {
        #pragma unroll
        for (int off = 16; off < 64; off <<= 1)
            #pragma unroll
            for (int ni = 0; ni < 4; ++ni)
                cs[ni] += __shfl_xor(cs[ni], off, 64);
        if (lane < 16) {
            float* dst = bufP + (size_t)(2 * bi + wave_m) * N_TOT + colBase;
            #pragma unroll
            for (int ni = 0; ni < 4; ++ni)
                dst[wave_n * 64 + ni * 16 + m16] = cs[ni];
        }
    }
}

// ---------------------------------------------------------------------------
// Kernel 2b: fused reduce + loss body. Block b (of 32) owns rows
// r = b*256+t: denom_r = sum of 128 partial slots (in-register), then
// contrib = log(denom_r - e^2) [- 4*pospart for blocks 0..15], block-reduced
// to partials[b]. Removes the denom round-trip and the second 8192-row pass.
// ---------------------------------------------------------------------------
__global__ __launch_bounds__(256) void reduce_kernel(
        const float* __restrict__ bufP, const float* __restrict__ pospart,
        float* __restrict__ partials) {
    const int b = blockIdx.x;                    // 0..31
    const int t = threadIdx.x;                   // 0..255
    const int r = b * 256 + t;                   // 0..8191
    float s0 = 0.f, s1 = 0.f, s2 = 0.f, s3 = 0.f;
    #pragma unroll 4
    for (int k = 0; k < NSLOT; k += 4) {
        s0 += bufP[(size_t)(k + 0) * N_TOT + r];
        s1 += bufP[(size_t)(k + 1) * N_TOT + r];
        s2 += bufP[(size_t)(k + 2) * N_TOT + r];
        s3 += bufP[(size_t)(k + 3) * N_TOT + r];
    }
    const float denom = (s0 + s1) + (s2 + s3);
    float contrib = logf(denom - E2);
    if (b < 16) contrib -= 4.0f * pospart[b * 256 + t];

    #pragma unroll
    for (int off = 32; off > 0; off >>= 1)
        contrib += __shfl_down(contrib, off);
    __shared__ float red[4];
    if ((t & 63) == 0) red[t >> 6] = contrib;
    __syncthreads();
    if (t == 0) partials[b] = (red[0] + red[1]) + (red[2] + red[3]);
}

// ---------------------------------------------------------------------------
// Kernel 3: out = sum(partials[0..31]) / 8192. One wave.
// ---------------------------------------------------------------------------
__global__ __launch_bounds__(64) void finalize_kernel(
        const float* __restrict__ partials, float* __restrict__ out) {
    const int t = threadIdx.x;                   // 0..63
    float s = (t < 32) ? partials[t] : 0.f;
    #pragma unroll
    for (int off = 32; off > 0; off >>= 1) s += __shfl_down(s, off);
    if (t == 0) out[0] = s / (float)N_TOT;
}

extern "C" void kernel_launch(void* const* d_in, const int* in_sizes, int n_in,
                              void* d_out, int out_size, void* d_ws, size_t ws_size,
                              hipStream_t stream) {
    const float* q = (const float*)d_in[0];
    const float* p = (const float*)d_in[1];
    // d_in[2] (neg) is normalized in the original but never used in the loss.
    float* out = (float*)d_out;

    // Workspace layout:
    //   Z        bf16 [8192*256]  @ 0       (4 MiB)
    //   bufP     f32  [128*8192]  @ 4 MiB   (4 MiB)  exp-sum partials
    //   pospart  f32  [4096]      after bufP
    //   partials f32  [32]        after pospart
    __hip_bfloat16* Z = (__hip_bfloat16*)d_ws;
    float* bufP     = (float*)((char*)d_ws + (size_t)N_TOT * D_DIM * sizeof(__hip_bfloat16));
    float* pospart  = bufP + (size_t)NSLOT * N_TOT;
    float* partials = pospart + B_ROWS;

    hipLaunchKernelGGL(norm_kernel, dim3(B_ROWS / 4), dim3(256), 0, stream,
                       q, p, Z, pospart);
    hipLaunchKernelGGL(simexp_gemm, dim3(NBLK), dim3(256), 0, stream, Z, bufP);
    hipLaunchKernelGGL(reduce_kernel, dim3(32), dim3(256), 0, stream,
                       bufP, pospart, partials);
    hipLaunchKernelGGL(finalize_kernel, dim3(1), dim3(64), 0, stream,
                       partials, out);
}

// Round 10
// 100.988 us; speedup vs baseline: 1.6786x; 1.0494x over previous
//
#include <hip/hip_runtime.h>
#include <hip/hip_bf16.h>
#include <math.h>

#define B_ROWS 4096
#define D_DIM  256
#define N_TOT  8192            // 2B
#define E2     7.38905609893065f   // exp(2) = diagonal term of the row sum
#define NTILE  64              // 8192 / 128
#define NBLK   (NTILE * (NTILE + 1) / 2)   // 2080 upper-triangle tile pairs
#define NSLOT  128             // 2 sub-slots per tile-row (wave_n / wave_m split)

typedef __attribute__((ext_vector_type(4))) float f32x4;
typedef __attribute__((ext_vector_type(8))) short bf16x8;   // 8 bf16 in 4 VGPRs

__device__ __forceinline__ void async_copy16(const void* gptr, void* lptr) {
    // NOTE: lptr is the WAVE-UNIFORM base; HW scatters lane*16 itself.
    __builtin_amdgcn_global_load_lds(
        (const __attribute__((address_space(1))) unsigned int*)gptr,
        (__attribute__((address_space(3))) unsigned int*)lptr,
        16 /*bytes*/, 0 /*offset*/, 0 /*aux*/);
}

__device__ __forceinline__ unsigned short bf16_bits(float x) {
    __hip_bfloat16 h = __float2bfloat16(x);
    return *reinterpret_cast<unsigned short*>(&h);
}

// ---------------------------------------------------------------------------
// Kernel 1: wave-per-row L2-normalize query & pos -> bf16 Z[8192][256]; per-
// row positive dot to pospart[row]. Vectorized f32x4 loads, pure shfl_xor
// reduce, no LDS, no barrier. Grid 1024 x 256 (R9-proven).
// ---------------------------------------------------------------------------
__global__ __launch_bounds__(256) void norm_kernel(
        const float* __restrict__ q, const float* __restrict__ p,
        __hip_bfloat16* __restrict__ Z, float* __restrict__ pospart) {
    const int t    = threadIdx.x;
    const int wv   = t >> 6;
    const int lane = t & 63;
    const int row  = blockIdx.x * 4 + wv;        // 0..4095

    const f32x4 qv = *(const f32x4*)(q + (size_t)row * D_DIM + lane * 4);
    const f32x4 pv = *(const f32x4*)(p + (size_t)row * D_DIM + lane * 4);
    float a = qv[0]*qv[0] + qv[1]*qv[1] + qv[2]*qv[2] + qv[3]*qv[3];
    float b = pv[0]*pv[0] + pv[1]*pv[1] + pv[2]*pv[2] + pv[3]*pv[3];
    float c = qv[0]*pv[0] + qv[1]*pv[1] + qv[2]*pv[2] + qv[3]*pv[3];
    #pragma unroll
    for (int off = 32; off > 0; off >>= 1) {
        a += __shfl_xor(a, off);
        b += __shfl_xor(b, off);
        c += __shfl_xor(c, off);
    }
    const float rq = 1.0f / fmaxf(sqrtf(a), 1e-12f);
    const float rp = 1.0f / fmaxf(sqrtf(b), 1e-12f);

    ushort4 zq, zp;
    zq.x = bf16_bits(qv[0] * rq); zq.y = bf16_bits(qv[1] * rq);
    zq.z = bf16_bits(qv[2] * rq); zq.w = bf16_bits(qv[3] * rq);
    zp.x = bf16_bits(pv[0] * rp); zp.y = bf16_bits(pv[1] * rp);
    zp.z = bf16_bits(pv[2] * rp); zp.w = bf16_bits(pv[3] * rp);
    *(ushort4*)(Z + (size_t)row * D_DIM + lane * 4)            = zq;
    *(ushort4*)(Z + (size_t)(B_ROWS + row) * D_DIM + lane * 4) = zp;
    if (lane == 0) pospart[row] = c * rq * rp;
}

// ---------------------------------------------------------------------------
// Kernel 2: fused S = Z*Z^T, upper-triangle tile pairs (symmetry), epilogue
// rowsum partials of exp(2*S) via collision-free plain stores (R8-proven).
// 128x128 tile, BK=64, 4 waves, single-buffered 32 KB LDS, 2 barriers/kt,
// u32-offset staging, XOR source swizzle.
// THIS ROUND: restore __launch_bounds__(256,3) — the R0-proven occupancy
// contract (VGPR cap 170: 76 VGPR + 64 AGPR = 140 fits; 3 waves/SIMD
// ceiling). R8's rewrite dropped it unmeasured; if the uncapped allocator
// drifted past 170 regs, occupancy silently fell below R0's.
// ---------------------------------------------------------------------------
__global__ __launch_bounds__(256, 3) void simexp_gemm(
        const __hip_bfloat16* __restrict__ Z, float* __restrict__ bufP) {
    __shared__ __hip_bfloat16 As[128 * 64];   // 16 KB, row stride 128 B
    __shared__ __hip_bfloat16 Bs[128 * 64];   // 16 KB
    const int tid    = threadIdx.x;
    const int lane   = tid & 63;
    const int wv     = tid >> 6;      // wave id 0..3
    const int wave_m = wv >> 1;       // 0..1  (row half)
    const int wave_n = wv & 1;        // 0..1  (col half)
    const int m16    = lane & 15;
    const int quad   = lane >> 4;

    // --- triangular decode: bid -> (bi <= bj) ---
    const int bid = blockIdx.x;
    int bi = (int)((129.0 - sqrt(129.0 * 129.0 - 8.0 * (double)bid)) * 0.5);
    while (bi > 0 && (bi * NTILE - bi * (bi - 1) / 2) > bid) --bi;
    while (((bi + 1) * NTILE - (bi + 1) * bi / 2) <= bid) ++bi;
    const int bj = bi + (bid - (bi * NTILE - bi * (bi - 1) / 2));
    const int rowBase = bi * 128;
    const int colBase = bj * 128;

    f32x4 acc[4][4];
    #pragma unroll
    for (int i = 0; i < 4; ++i)
        #pragma unroll
        for (int j = 0; j < 4; ++j) acc[i][j] = (f32x4){0.f, 0.f, 0.f, 0.f};

    // staging geometry: one instr = 64 lanes x 16B = 8 rows of 128B.
    // lane l -> local row (l>>3), chunk slot (l&7); LDS chunk c of row r
    // holds global chunk c ^ (r&7) (xor involution). u32 byte offsets.
    const int lrow = lane >> 3;
    const int lchk = lane & 7;
    unsigned int aoff[4], boff[4];
    #pragma unroll
    for (int pp = 0; pp < 4; ++pp) {
        const int r = wv * 32 + pp * 8 + lrow;          // local row 0..127
        const int g = lchk ^ (r & 7);                   // swizzled global chunk
        aoff[pp] = (unsigned int)((rowBase + r) * 512 + g * 16);
        boff[pp] = (unsigned int)((colBase + r) * 512 + g * 16);
    }

    for (int kt = 0; kt < 4; ++kt) {
        __syncthreads();   // previous iter's LDS reads done before overwrite
        #pragma unroll
        for (int pp = 0; pp < 4; ++pp) {
            async_copy16((const char*)Z + aoff[pp],
                         (char*)As + (wv * 32 + pp * 8) * 128);
            async_copy16((const char*)Z + boff[pp],
                         (char*)Bs + (wv * 32 + pp * 8) * 128);
            aoff[pp] += 128;   // next K-chunk (64 elems = 128 B)
            boff[pp] += 128;
        }
        __syncthreads();   // drains vmcnt: staging complete

        #pragma unroll
        for (int kt2 = 0; kt2 < 2; ++kt2) {
            const int sw = (kt2 * 4 + quad) ^ (m16 & 7);  // swizzled chunk
            const unsigned int abase =
                (unsigned int)((wave_m * 64 + m16) * 128 + sw * 16);
            const unsigned int bbase =
                (unsigned int)((wave_n * 64 + m16) * 128 + sw * 16);
            bf16x8 af[4], bfr[4];
            #pragma unroll
            for (int mi = 0; mi < 4; ++mi)
                af[mi] = *(const bf16x8*)((const char*)As + abase + mi * 2048);
            #pragma unroll
            for (int ni = 0; ni < 4; ++ni)
                bfr[ni] = *(const bf16x8*)((const char*)Bs + bbase + ni * 2048);
            #pragma unroll
            for (int mi = 0; mi < 4; ++mi)
                #pragma unroll
                for (int ni = 0; ni < 4; ++ni)
                    acc[mi][ni] = __builtin_amdgcn_mfma_f32_16x16x32_bf16(
                        af[mi], bfr[ni], acc[mi][ni], 0, 0, 0);
        }
    }

    // --- epilogue: exp(2s) once; row partials and col partials ---
    // C/D layout: col = lane&15, row = quad*4 + reg  [m89-verified].
    float cs[4] = {0.f, 0.f, 0.f, 0.f};
    float rs[4][4];
    #pragma unroll
    for (int mi = 0; mi < 4; ++mi)
        #pragma unroll
        for (int r = 0; r < 4; ++r) {
            float s = 0.f;
            #pragma unroll
            for (int ni = 0; ni < 4; ++ni) {
                const float e = __expf(2.0f * acc[mi][ni][r]);
                s += e;
                cs[ni] += e;
            }
            rs[mi][r] = s;
        }
    // row sums: reduce across the 16 columns (lanes sharing a quad)
    #pragma unroll
    for (int off = 1; off < 16; off <<= 1)
        #pragma unroll
        for (int mi = 0; mi < 4; ++mi)
            #pragma unroll
            for (int r = 0; r < 4; ++r)
                rs[mi][r] += __shfl_xor(rs[mi][r], off, 64);
    if (m16 == 0) {
        float* dst = bufP + (size_t)(2 * bj + wave_n) * N_TOT + rowBase;
        #pragma unroll
        for (int mi = 0; mi < 4; ++mi)
            #pragma unroll
            for (int r = 0; r < 4; ++r)
                dst[wave_m * 64 + mi * 16 + quad * 4 + r] = rs[mi][r];
    }
    // col sums: reduce across the 4 quads (rows) -> symmetric contribution
    if (bi != bj) {
        #pragma unroll
        for (int off = 16; off < 64; off <<= 1)
            #pragma unroll
            for (int ni = 0; ni < 4; ++ni)
                cs[ni] += __shfl_xor(cs[ni], off, 64);
        if (lane < 16) {
            float* dst = bufP + (size_t)(2 * bi + wave_m) * N_TOT + colBase;
            #pragma unroll
            for (int ni = 0; ni < 4; ++ni)
                dst[wave_n * 64 + ni * 16 + m16] = cs[ni];
        }
    }
}

// ---------------------------------------------------------------------------
// Kernel 2b: fused reduce + loss body. Block b (of 32) owns rows r=b*256+t.
// THIS ROUND: 8 independent accumulator chains, fully unrolled — the R9
// version's 4 chains serialized ~32 L2 round-trips (~4 us); 8 chains with
// full unroll lets the loads issue in a couple of latency waves.
// ---------------------------------------------------------------------------
__global__ __launch_bounds__(256) void reduce_kernel(
        const float* __restrict__ bufP, const float* __restrict__ pospart,
        float* __restrict__ partials) {
    const int b = blockIdx.x;                    // 0..31
    const int t = threadIdx.x;                   // 0..255
    const int r = b * 256 + t;                   // 0..8191
    float s[8] = {0.f, 0.f, 0.f, 0.f, 0.f, 0.f, 0.f, 0.f};
    #pragma unroll
    for (int k = 0; k < NSLOT; k += 8) {
        #pragma unroll
        for (int j = 0; j < 8; ++j)
            s[j] += bufP[(size_t)(k + j) * N_TOT + r];
    }
    const float denom = ((s[0] + s[1]) + (s[2] + s[3]))
                      + ((s[4] + s[5]) + (s[6] + s[7]));
    float contrib = logf(denom - E2);
    if (b < 16) contrib -= 4.0f * pospart[b * 256 + t];

    #pragma unroll
    for (int off = 32; off > 0; off >>= 1)
        contrib += __shfl_down(contrib, off);
    __shared__ float red[4];
    if ((t & 63) == 0) red[t >> 6] = contrib;
    __syncthreads();
    if (t == 0) partials[b] = (red[0] + red[1]) + (red[2] + red[3]);
}

// ---------------------------------------------------------------------------
// Kernel 3: out = sum(partials[0..31]) / 8192. One wave.
// ---------------------------------------------------------------------------
__global__ __launch_bounds__(64) void finalize_kernel(
        const float* __restrict__ partials, float* __restrict__ out) {
    const int t = threadIdx.x;                   // 0..63
    float s = (t < 32) ? partials[t] : 0.f;
    #pragma unroll
    for (int off = 32; off > 0; off >>= 1) s += __shfl_down(s, off);
    if (t == 0) out[0] = s / (float)N_TOT;
}

extern "C" void kernel_launch(void* const* d_in, const int* in_sizes, int n_in,
                              void* d_out, int out_size, void* d_ws, size_t ws_size,
                              hipStream_t stream) {
    const float* q = (const float*)d_in[0];
    const float* p = (const float*)d_in[1];
    // d_in[2] (neg) is normalized in the original but never used in the loss.
    float* out = (float*)d_out;

    // Workspace layout:
    //   Z        bf16 [8192*256]  @ 0       (4 MiB)
    //   bufP     f32  [128*8192]  @ 4 MiB   (4 MiB)  exp-sum partials
    //   pospart  f32  [4096]      after bufP
    //   partials f32  [32]        after pospart
    __hip_bfloat16* Z = (__hip_bfloat16*)d_ws;
    float* bufP     = (float*)((char*)d_ws + (size_t)N_TOT * D_DIM * sizeof(__hip_bfloat16));
    float* pospart  = bufP + (size_t)NSLOT * N_TOT;
    float* partials = pospart + B_ROWS;

    hipLaunchKernelGGL(norm_kernel, dim3(B_ROWS / 4), dim3(256), 0, stream,
                       q, p, Z, pospart);
    hipLaunchKernelGGL(simexp_gemm, dim3(NBLK), dim3(256), 0, stream, Z, bufP);
    hipLaunchKernelGGL(reduce_kernel, dim3(32), dim3(256), 0, stream,
                       bufP, pospart, partials);
    hipLaunchKernelGGL(finalize_kernel, dim3(1), dim3(64), 0, stream,
                       partials, out);
}

// Round 11
// 98.499 us; speedup vs baseline: 1.7210x; 1.0253x over previous
//
#include <hip/hip_runtime.h>
#include <hip/hip_bf16.h>
#include <math.h>

#define B_ROWS 4096
#define D_DIM  256
#define N_TOT  8192            // 2B
#define E2     7.38905609893065f   // exp(2) = diagonal term of the row sum
#define NTILE  64              // 8192 / 128
#define NBLK   (NTILE * (NTILE + 1) / 2)   // 2080 upper-triangle tile pairs
#define NSLOT  128             // 2 sub-slots per tile-row (wave_n / wave_m split)

typedef __attribute__((ext_vector_type(4))) float f32x4;
typedef __attribute__((ext_vector_type(8))) short bf16x8;   // 8 bf16 in 4 VGPRs

__device__ __forceinline__ void async_copy16(const void* gptr, void* lptr) {
    // NOTE: lptr is the WAVE-UNIFORM base; HW scatters lane*16 itself.
    __builtin_amdgcn_global_load_lds(
        (const __attribute__((address_space(1))) unsigned int*)gptr,
        (__attribute__((address_space(3))) unsigned int*)lptr,
        16 /*bytes*/, 0 /*offset*/, 0 /*aux*/);
}

__device__ __forceinline__ unsigned short bf16_bits(float x) {
    __hip_bfloat16 h = __float2bfloat16(x);
    return *reinterpret_cast<unsigned short*>(&h);
}

// ---------------------------------------------------------------------------
// Kernel 1: wave-per-row L2-normalize query & pos -> bf16 Z[8192][256]; per-
// row positive dot to pospart[row]. Vectorized f32x4 loads, pure shfl_xor
// reduce, no LDS, no barrier. Grid 1024 x 256 (R9-proven).
// Block 0 also zeroes out[0] (kernel-boundary ordering covers the merged
// reduce's atomicAdd accumulation).
// ---------------------------------------------------------------------------
__global__ __launch_bounds__(256) void norm_kernel(
        const float* __restrict__ q, const float* __restrict__ p,
        __hip_bfloat16* __restrict__ Z, float* __restrict__ pospart,
        float* __restrict__ out) {
    const int t    = threadIdx.x;
    const int wv   = t >> 6;
    const int lane = t & 63;
    const int row  = blockIdx.x * 4 + wv;        // 0..4095
    if (blockIdx.x == 0 && t == 0) out[0] = 0.0f;

    const f32x4 qv = *(const f32x4*)(q + (size_t)row * D_DIM + lane * 4);
    const f32x4 pv = *(const f32x4*)(p + (size_t)row * D_DIM + lane * 4);
    float a = qv[0]*qv[0] + qv[1]*qv[1] + qv[2]*qv[2] + qv[3]*qv[3];
    float b = pv[0]*pv[0] + pv[1]*pv[1] + pv[2]*pv[2] + pv[3]*pv[3];
    float c = qv[0]*pv[0] + qv[1]*pv[1] + qv[2]*pv[2] + qv[3]*pv[3];
    #pragma unroll
    for (int off = 32; off > 0; off >>= 1) {
        a += __shfl_xor(a, off);
        b += __shfl_xor(b, off);
        c += __shfl_xor(c, off);
    }
    const float rq = 1.0f / fmaxf(sqrtf(a), 1e-12f);
    const float rp = 1.0f / fmaxf(sqrtf(b), 1e-12f);

    ushort4 zq, zp;
    zq.x = bf16_bits(qv[0] * rq); zq.y = bf16_bits(qv[1] * rq);
    zq.z = bf16_bits(qv[2] * rq); zq.w = bf16_bits(qv[3] * rq);
    zp.x = bf16_bits(pv[0] * rp); zp.y = bf16_bits(pv[1] * rp);
    zp.z = bf16_bits(pv[2] * rp); zp.w = bf16_bits(pv[3] * rp);
    *(ushort4*)(Z + (size_t)row * D_DIM + lane * 4)            = zq;
    *(ushort4*)(Z + (size_t)(B_ROWS + row) * D_DIM + lane * 4) = zp;
    if (lane == 0) pospart[row] = c * rq * rp;
}

// ---------------------------------------------------------------------------
// Kernel 2: fused S = Z*Z^T, upper-triangle tile pairs (symmetry), epilogue
// rowsum partials of exp(2*S) via collision-free plain stores. FROZEN:
// R0 structure (128x128 tile, BK=64, 4 waves, single-buffered 32 KB LDS,
// 2 barriers/kt) + u32-offset staging + XOR source swizzle +
// __launch_bounds__(256,3) (R10-proven: 101 us total).
//   row-partials of block (bi,bj) -> slot 2*bj+wave_n, rows of tile bi
//   col-partials of block (bi,bj) -> slot 2*bi+wave_m, cols of tile bj
// Every slot of bufP[128][8192] written exactly once; no init, no atomics.
// ---------------------------------------------------------------------------
__global__ __launch_bounds__(256, 3) void simexp_gemm(
        const __hip_bfloat16* __restrict__ Z, float* __restrict__ bufP) {
    __shared__ __hip_bfloat16 As[128 * 64];   // 16 KB, row stride 128 B
    __shared__ __hip_bfloat16 Bs[128 * 64];   // 16 KB
    const int tid    = threadIdx.x;
    const int lane   = tid & 63;
    const int wv     = tid >> 6;      // wave id 0..3
    const int wave_m = wv >> 1;       // 0..1  (row half)
    const int wave_n = wv & 1;        // 0..1  (col half)
    const int m16    = lane & 15;
    const int quad   = lane >> 4;

    // --- triangular decode: bid -> (bi <= bj) ---
    const int bid = blockIdx.x;
    int bi = (int)((129.0 - sqrt(129.0 * 129.0 - 8.0 * (double)bid)) * 0.5);
    while (bi > 0 && (bi * NTILE - bi * (bi - 1) / 2) > bid) --bi;
    while (((bi + 1) * NTILE - (bi + 1) * bi / 2) <= bid) ++bi;
    const int bj = bi + (bid - (bi * NTILE - bi * (bi - 1) / 2));
    const int rowBase = bi * 128;
    const int colBase = bj * 128;

    f32x4 acc[4][4];
    #pragma unroll
    for (int i = 0; i < 4; ++i)
        #pragma unroll
        for (int j = 0; j < 4; ++j) acc[i][j] = (f32x4){0.f, 0.f, 0.f, 0.f};

    // staging geometry: one instr = 64 lanes x 16B = 8 rows of 128B.
    // lane l -> local row (l>>3), chunk slot (l&7); LDS chunk c of row r
    // holds global chunk c ^ (r&7) (xor involution). u32 byte offsets.
    const int lrow = lane >> 3;
    const int lchk = lane & 7;
    unsigned int aoff[4], boff[4];
    #pragma unroll
    for (int pp = 0; pp < 4; ++pp) {
        const int r = wv * 32 + pp * 8 + lrow;          // local row 0..127
        const int g = lchk ^ (r & 7);                   // swizzled global chunk
        aoff[pp] = (unsigned int)((rowBase + r) * 512 + g * 16);
        boff[pp] = (unsigned int)((colBase + r) * 512 + g * 16);
    }

    for (int kt = 0; kt < 4; ++kt) {
        __syncthreads();   // previous iter's LDS reads done before overwrite
        #pragma unroll
        for (int pp = 0; pp < 4; ++pp) {
            async_copy16((const char*)Z + aoff[pp],
                         (char*)As + (wv * 32 + pp * 8) * 128);
            async_copy16((const char*)Z + boff[pp],
                         (char*)Bs + (wv * 32 + pp * 8) * 128);
            aoff[pp] += 128;   // next K-chunk (64 elems = 128 B)
            boff[pp] += 128;
        }
        __syncthreads();   // drains vmcnt: staging complete

        #pragma unroll
        for (int kt2 = 0; kt2 < 2; ++kt2) {
            const int sw = (kt2 * 4 + quad) ^ (m16 & 7);  // swizzled chunk
            const unsigned int abase =
                (unsigned int)((wave_m * 64 + m16) * 128 + sw * 16);
            const unsigned int bbase =
                (unsigned int)((wave_n * 64 + m16) * 128 + sw * 16);
            bf16x8 af[4], bfr[4];
            #pragma unroll
            for (int mi = 0; mi < 4; ++mi)
                af[mi] = *(const bf16x8*)((const char*)As + abase + mi * 2048);
            #pragma unroll
            for (int ni = 0; ni < 4; ++ni)
                bfr[ni] = *(const bf16x8*)((const char*)Bs + bbase + ni * 2048);
            #pragma unroll
            for (int mi = 0; mi < 4; ++mi)
                #pragma unroll
                for (int ni = 0; ni < 4; ++ni)
                    acc[mi][ni] = __builtin_amdgcn_mfma_f32_16x16x32_bf16(
                        af[mi], bfr[ni], acc[mi][ni], 0, 0, 0);
        }
    }

    // --- epilogue: exp(2s) once; row partials and col partials ---
    // C/D layout: col = lane&15, row = quad*4 + reg  [m89-verified].
    float cs[4] = {0.f, 0.f, 0.f, 0.f};
    float rs[4][4];
    #pragma unroll
    for (int mi = 0; mi < 4; ++mi)
        #pragma unroll
        for (int r = 0; r < 4; ++r) {
            float s = 0.f;
            #pragma unroll
            for (int ni = 0; ni < 4; ++ni) {
                const float e = __expf(2.0f * acc[mi][ni][r]);
                s += e;
                cs[ni] += e;
            }
            rs[mi][r] = s;
        }
    // row sums: reduce across the 16 columns (lanes sharing a quad)
    #pragma unroll
    for (int off = 1; off < 16; off <<= 1)
        #pragma unroll
        for (int mi = 0; mi < 4; ++mi)
            #pragma unroll
            for (int r = 0; r < 4; ++r)
                rs[mi][r] += __shfl_xor(rs[mi][r], off, 64);
    if (m16 == 0) {
        float* dst = bufP + (size_t)(2 * bj + wave_n) * N_TOT + rowBase;
        #pragma unroll
        for (int mi = 0; mi < 4; ++mi)
            #pragma unroll
            for (int r = 0; r < 4; ++r)
                dst[wave_m * 64 + mi * 16 + quad * 4 + r] = rs[mi][r];
    }
    // col sums: reduce across the 4 quads (rows) -> symmetric contribution
    if (bi != bj) {
        #pragma unroll
        for (int off = 16; off < 64; off <<= 1)
            #pragma unroll
            for (int ni = 0; ni < 4; ++ni)
                cs[ni] += __shfl_xor(cs[ni], off, 64);
        if (lane < 16) {
            float* dst = bufP + (size_t)(2 * bi + wave_m) * N_TOT + colBase;
            #pragma unroll
            for (int ni = 0; ni < 4; ++ni)
                dst[wave_n * 64 + ni * 16 + m16] = cs[ni];
        }
    }
}

// ---------------------------------------------------------------------------
// Kernel 2b (merged reduce + finalize): block b of 32 owns rows r=b*256+t.
// denom_r = sum of 128 partial slots (8 independent chains, R10-proven),
// contrib = log(denom_r - e^2) [- 4*pospart], block-reduced; thread 0
// atomicAdds block_sum/8192 into out[0] (zeroed by norm_kernel; 32 f32
// atomics, order-independence error ~1e-7 rel). Removes the finalize
// launch (~3-4 us of dispatch overhead per the R9/R10 budget analysis).
// ---------------------------------------------------------------------------
__global__ __launch_bounds__(256) void reduce_kernel(
        const float* __restrict__ bufP, const float* __restrict__ pospart,
        float* __restrict__ out) {
    const int b = blockIdx.x;                    // 0..31
    const int t = threadIdx.x;                   // 0..255
    const int r = b * 256 + t;                   // 0..8191
    float s[8] = {0.f, 0.f, 0.f, 0.f, 0.f, 0.f, 0.f, 0.f};
    #pragma unroll
    for (int k = 0; k < NSLOT; k += 8) {
        #pragma unroll
        for (int j = 0; j < 8; ++j)
            s[j] += bufP[(size_t)(k + j) * N_TOT + r];
    }
    const float denom = ((s[0] + s[1]) + (s[2] + s[3]))
                      + ((s[4] + s[5]) + (s[6] + s[7]));
    float contrib = logf(denom - E2);
    if (b < 16) contrib -= 4.0f * pospart[b * 256 + t];

    #pragma unroll
    for (int off = 32; off > 0; off >>= 1)
        contrib += __shfl_down(contrib, off);
    __shared__ float red[4];
    if ((t & 63) == 0) red[t >> 6] = contrib;
    __syncthreads();
    if (t == 0) {
        const float bs = (red[0] + red[1]) + (red[2] + red[3]);
        atomicAdd(out, bs / (float)N_TOT);
    }
}

extern "C" void kernel_launch(void* const* d_in, const int* in_sizes, int n_in,
                              void* d_out, int out_size, void* d_ws, size_t ws_size,
                              hipStream_t stream) {
    const float* q = (const float*)d_in[0];
    const float* p = (const float*)d_in[1];
    // d_in[2] (neg) is normalized in the original but never used in the loss.
    float* out = (float*)d_out;

    // Workspace layout:
    //   Z        bf16 [8192*256]  @ 0       (4 MiB)
    //   bufP     f32  [128*8192]  @ 4 MiB   (4 MiB)  exp-sum partials
    //   pospart  f32  [4096]      after bufP
    __hip_bfloat16* Z = (__hip_bfloat16*)d_ws;
    float* bufP     = (float*)((char*)d_ws + (size_t)N_TOT * D_DIM * sizeof(__hip_bfloat16));
    float* pospart  = bufP + (size_t)NSLOT * N_TOT;

    hipLaunchKernelGGL(norm_kernel, dim3(B_ROWS / 4), dim3(256), 0, stream,
                       q, p, Z, pospart, out);
    hipLaunchKernelGGL(simexp_gemm, dim3(NBLK), dim3(256), 0, stream, Z, bufP);
    hipLaunchKernelGGL(reduce_kernel, dim3(32), dim3(256), 0, stream,
                       bufP, pospart, out);
}